// Round 4
// baseline (1390.342 us; speedup 1.0000x reference)
//
#include <hip/hip_runtime.h>

typedef unsigned int u32;
typedef unsigned short u16;
typedef unsigned long long u64;
typedef _Float16 h2 __attribute__((ext_vector_type(2)));
typedef _Float16 h4 __attribute__((ext_vector_type(4)));
typedef _Float16 h8 __attribute__((ext_vector_type(8)));
typedef float f4 __attribute__((ext_vector_type(4)));

#define ROWS 65536   // B*A
#define NB 1024
#define NA 64

__device__ __forceinline__ float dot4(float4 w, float4 x){
  return w.x*x.x + w.y*x.y + w.z*x.z + w.w*x.w;
}
__device__ __forceinline__ h2 u32_h2(u32 v){ union { u32 u; h2 h; } x; x.u = v; return x.h; }
__device__ __forceinline__ h2 pack_h2(float a, float b){ h2 r; r.x = (_Float16)a; r.y = (_Float16)b; return r; }
__device__ __forceinline__ h4 pack_h4(float4 v){
  h4 r; r.x=(_Float16)v.x; r.y=(_Float16)v.y; r.z=(_Float16)v.z; r.w=(_Float16)v.w; return r;
}
__device__ __forceinline__ h4 pack_h4_relu(float4 v){
  h4 r; r.x=(_Float16)fmaxf(v.x,0.f); r.y=(_Float16)fmaxf(v.y,0.f);
  r.z=(_Float16)fmaxf(v.z,0.f); r.w=(_Float16)fmaxf(v.w,0.f); return r;
}
// fast sigmoid/tanh on v_exp_f32 + v_rcp_f32 (~1 ulp each; threshold is 1.1e-2)
__device__ __forceinline__ float fsig(float z){
  float e = __builtin_amdgcn_exp2f(-1.44269504f * z);
  return __builtin_amdgcn_rcpf(1.0f + e);
}
__device__ __forceinline__ float ftanh(float z){
  float e = __builtin_amdgcn_exp2f(2.885390082f * z);
  return 1.0f - 2.0f * __builtin_amdgcn_rcpf(1.0f + e);
}
__device__ __forceinline__ h8 load8f(const float* p){
  float4 a = *(const float4*)p;
  float4 b = *(const float4*)(p + 4);
  h8 r;
  r[0] = (_Float16)a.x; r[1] = (_Float16)a.y; r[2] = (_Float16)a.z; r[3] = (_Float16)a.w;
  r[4] = (_Float16)b.x; r[5] = (_Float16)b.y; r[6] = (_Float16)b.z; r[7] = (_Float16)b.w;
  return r;
}
__device__ __forceinline__ float bperm_f(int addr, float v){
  return __int_as_float(__builtin_amdgcn_ds_bpermute(addr, __float_as_int(v)));
}

// ---------------- weight f16 pre-convert (actor_2 weights) ----------------
__global__ __launch_bounds__(256) void k_cvt(
    const float* __restrict__ a2w1, const float* __restrict__ a2w2,
    _Float16* __restrict__ w1h, _Float16* __restrict__ w2h)
{
  int i = blockIdx.x * 256 + threadIdx.x;
  if (i < 32768) w1h[i] = (_Float16)a2w1[i];
  if (i < 8192)  w2h[i] = (_Float16)a2w2[i];
}

// ---------------- actor_1 + attention: 8 rows per block, 128 threads ----------------
// kept f32/VALU: feeds the DISCRETE decisions (isinit threshold, K-nearest argsort) where
// f16 rounding (~1e-3) could flip group membership and blow up absmax.
__global__ __launch_bounds__(128) void k_actor1(
    const float* __restrict__ obs, const float* __restrict__ w1, const float* __restrict__ b1,
    const float* __restrict__ lng, const float* __restrict__ lnb,
    const float* __restrict__ w2, const float* __restrict__ b2,
    const float* __restrict__ aw1, const float* __restrict__ ab1,
    const float* __restrict__ aw2, const float* __restrict__ ab2,
    const float* __restrict__ aw3, const float* __restrict__ ab3,
    float* __restrict__ thoughts, int* __restrict__ isinit)
{
  const int b0 = blockIdx.x * 8;
  const int t = threadIdx.x;
  __shared__ float4 xs[8][64];     // 8 obs rows (256 f32 each)
  __shared__ float hs[8][128];     // relu(LN(h))
  __shared__ float tb[8][128];     // thoughts
  __shared__ float ab[8][64];
  __shared__ float a2b[8][64];
  __shared__ float red[8][4];

  { const float4* og = (const float4*)(obs + (size_t)b0 * 256);
    #pragma unroll
    for (int j = 0; j < 4; j++){ int p = j * 128 + t; xs[p >> 6][p & 63] = og[p]; } }
  __syncthreads();

  // h = obs @ W1^T + b1   (thread t owns output feature t, streams W1 row t)
  float acc[8];
  #pragma unroll
  for (int r = 0; r < 8; r++) acc[r] = b1[t];
  { const float4* wr = (const float4*)(w1 + (size_t)t * 256);
    for (int j = 0; j < 64; j++){
      float4 w = wr[j];
      #pragma unroll
      for (int r = 0; r < 8; r++) acc[r] += dot4(w, xs[r][j]);
    } }

  // LayerNorm over 128 features (block = 2 waves)
  #pragma unroll
  for (int r = 0; r < 8; r++){
    float s = acc[r], s2 = acc[r] * acc[r];
    #pragma unroll
    for (int off = 32; off > 0; off >>= 1){ s += __shfl_down(s, off); s2 += __shfl_down(s2, off); }
    if ((t & 63) == 0){ red[r][t >> 6] = s; red[r][2 + (t >> 6)] = s2; }
  }
  __syncthreads();
  const float g_ = lng[t], bb_ = lnb[t];
  #pragma unroll
  for (int r = 0; r < 8; r++){
    float mu  = (red[r][0] + red[r][1]) * (1.0f/128.0f);
    float var = (red[r][2] + red[r][3]) * (1.0f/128.0f) - mu * mu;
    hs[r][t] = fmaxf((acc[r] - mu) * rsqrtf(var + 1e-5f) * g_ + bb_, 0.0f);
  }
  __syncthreads();

  // thoughts = relu(h) @ W2^T + b2
  float acc2[8];
  #pragma unroll
  for (int r = 0; r < 8; r++) acc2[r] = b2[t];
  { const float4* wr = (const float4*)(w2 + (size_t)t * 128);
    for (int j = 0; j < 32; j++){
      float4 w = wr[j];
      #pragma unroll
      for (int r = 0; r < 8; r++) acc2[r] += dot4(w, ((const float4*)hs[r])[j]);
    } }
  #pragma unroll
  for (int r = 0; r < 8; r++){
    thoughts[(size_t)(b0 + r) * 128 + t] = acc2[r];
    tb[r][t] = acc2[r];
  }
  __syncthreads();

  // attention MLP
  if (t < 64){
    float a[8];
    #pragma unroll
    for (int r = 0; r < 8; r++) a[r] = ab1[t];
    const float4* wr = (const float4*)(aw1 + (size_t)t * 128);
    for (int j = 0; j < 32; j++){
      float4 w = wr[j];
      #pragma unroll
      for (int r = 0; r < 8; r++) a[r] += dot4(w, ((const float4*)tb[r])[j]);
    }
    #pragma unroll
    for (int r = 0; r < 8; r++) ab[r][t] = fmaxf(a[r], 0.0f);
  }
  __syncthreads();
  if (t < 64){
    float a[8];
    #pragma unroll
    for (int r = 0; r < 8; r++) a[r] = ab2[t];
    const float4* wr = (const float4*)(aw2 + (size_t)t * 64);
    for (int j = 0; j < 16; j++){
      float4 w = wr[j];
      #pragma unroll
      for (int r = 0; r < 8; r++) a[r] += dot4(w, ((const float4*)ab[r])[j]);
    }
    #pragma unroll
    for (int r = 0; r < 8; r++) a2b[r][t] = fmaxf(a[r], 0.0f);
  }
  __syncthreads();
  if (t < 8){
    float p = ab3[0];
    for (int j = 0; j < 64; j++) p += aw3[j] * a2b[t][j];
    isinit[b0 + t] = (p > 0.0f) ? 1 : 0;   // sigmoid(p) > 0.5  <=>  p > 0
  }
}

// ---------------- K-nearest groups: one block per batch ----------------
__global__ __launch_bounds__(256) void k_groups(
    const float* __restrict__ thoughts, int* __restrict__ idxout)
{
  const int b = blockIdx.x;
  const int tid = threadIdx.x;
  __shared__ float T[64 * 130];
  __shared__ float sq[64];
  for (int p = tid; p < 8192; p += 256){
    T[(p >> 7) * 130 + (p & 127)] = thoughts[(size_t)b * 8192 + p];
  }
  __syncthreads();
  if (tid < 64){
    const float2* tj = (const float2*)&T[tid * 130];
    float s = 0.0f;
    #pragma unroll 8
    for (int k = 0; k < 64; k++){ float2 v = tj[k]; s += v.x*v.x + v.y*v.y; }
    sq[tid] = s;
  }
  __syncthreads();
  const int lane = tid & 63;
  const int wv = tid >> 6;
  const float2* tj = (const float2*)&T[lane * 130];
  const float sqj = sq[lane];
  for (int ii = 0; ii < 16; ii++){
    const int i = wv * 16 + ii;
    const float2* ti = (const float2*)&T[i * 130];
    float dot = 0.0f;
    #pragma unroll 8
    for (int k = 0; k < 64; k++){ float2 a = ti[k]; float2 c = tj[k]; dot += a.x*c.x + a.y*c.y; }
    float d = fmaxf(sq[i] + sqj - 2.0f*dot, 0.0f);   // clamp keeps uint-compare == float-compare
    u64 key = (((u64)__float_as_uint(d)) << 32) | (u32)lane;
    u64 mask = 0;
    for (int q = 0; q < 8; q++){
      u64 m = key;
      #pragma unroll
      for (int off = 32; off > 0; off >>= 1){ u64 o = __shfl_xor(m, off); if (o < m) m = o; }
      mask |= 1ull << (u32)(m & 63u);
      if (key == m) key = ~0ull;
    }
    if (lane == 0){
      u64 mm = mask;
      int base = (b * 64 + i) * 8;
      #pragma unroll
      for (int q = 0; q < 8; q++){ int j = (int)__builtin_ctzll(mm); mm &= mm - 1; idxout[base + q] = j; }
    }
  }
}

// ---------------- sequential gather -> bi-LSTM -> scatter: one block per batch ----------------
// v5: BARRIER-FREE recurrence. Waves 0 (fwd) / 4 (bwd) each own the ENTIRE 8-step recurrence
// for their direction: lane l computes gates/c/hn for h-row l; h is redistributed to the MFMA
// A-fragment layout IN-REGISTER via 16 ds_bpermute + f16 packs (no LDS h buffer, no barrier).
// Per step: 32 mfma (16 tiles x K=64, all-A-rows=h duplicate trick, C=0), lane selects its
// tile by hi, z = sel(acc) + Zx. Barriers per initiator: 2 (was 9).
// Phase A (Zx = bias + X @ Wih^T) runs on the other 6 waves: per dir 16 coltiles split {6,6,4},
// Bf = 24 h8 = 96 VGPR. W[32] is a REGISTER UNION: A-waves keep Wih fragments, B-waves keep
// Whh fragments (128 VGPR) -> allocation ~240 <= 256, 1 block/CU (traded for the 3x shorter
// serial chain). MFMA conventions (verified v3/v4): A row = lane&15, B col = lane&15,
// k = kt*32 + (lane>>4)*8 + j, C: col = lane&15, row = (lane>>4)*4 + reg.
__global__ __launch_bounds__(512) void k_scan(
    const float* __restrict__ thoughts, const int* __restrict__ isinit, const int* __restrict__ idx,
    const float* __restrict__ wihf, const float* __restrict__ whhf,
    const float* __restrict__ bihf, const float* __restrict__ bhhf,
    const float* __restrict__ wihb, const float* __restrict__ whhb,
    const float* __restrict__ bihb, const float* __restrict__ bhhb,
    float* __restrict__ newt)
{
  const int b    = blockIdx.x;
  const int tid  = threadIdx.x;
  const int w    = tid >> 6;          // wave 0..7
  const int lane = tid & 63;
  const int dir  = w >> 2;            // waves 0-3 fwd, 4-7 bwd
  const int wsub = w & 3;             // 0 -> recurrence wave; 1..3 -> phase-A waves
  const int lr   = lane & 15;
  const int hi   = lane >> 4;
  const bool isB = (wsub == 0);

  __shared__ __align__(16) _Float16 nt16[64 * 136];  // f16 state mirror, padded (17408 B)
  __shared__ __align__(16) _Float16 Zx16[2*8*64*4];  // input projection (+bias), f16 (8192 B)
  __shared__ int gall[512];
  __shared__ int flags[64];
  __shared__ int dirty[64];

  const float* wih = dir ? wihb : wihf;
  const float* whh = dir ? whhb : whhf;

  // ---- weight fragments (register union) ----
  // A-waves (wsub 1..3): W[k*4+kt] = Wih coltile (ai*6+k), kt<4   (<=96 VGPR)
  // B-waves (wsub == 0): W[ct*2+kt] = Whh coltile ct, kt<2        (128 VGPR)
  h8 W[32];
  float biasl[6];
  if (isB){
    #pragma unroll
    for (int ct = 0; ct < 16; ct++){
      const int n = ((ct >> 2) << 6) + ((ct & 3) << 4) + lr;
      const float* wr = whh + (size_t)n * 64 + (hi << 3);
      W[ct * 2 + 0] = load8f(wr);
      W[ct * 2 + 1] = load8f(wr + 32);
      __builtin_amdgcn_sched_barrier(0);
    }
  } else {
    const int ai = wsub - 1;
    const float* bih = dir ? bihb : bihf;
    const float* bhh = dir ? bhhb : bhhf;
    #pragma unroll
    for (int k = 0; k < 6; k++){
      const int ct = ai * 6 + k;
      if (ct < 16){
        const int n = ((ct >> 2) << 6) + ((ct & 3) << 4) + lr;
        const float* wr = wih + (size_t)n * 128 + (hi << 3);
        #pragma unroll
        for (int kt = 0; kt < 4; kt++) W[k * 4 + kt] = load8f(wr + kt * 32);
        biasl[k] = bih[n] + bhh[n];
      }
      __builtin_amdgcn_sched_barrier(0);
    }
  }

  { const float4* tf4 = (const float4*)(thoughts + (size_t)b * 8192);
    #pragma unroll
    for (int k2 = 0; k2 < 4; k2++){
      int id4 = tid + k2 * 512;                 // f4 index, 2048 total (32 f4 per row)
      float4 v = tf4[id4];
      *(h4*)&nt16[(id4 >> 5) * 136 + (id4 & 31) * 4] = pack_h4(v);
    } }
  gall[tid] = idx[(size_t)b * 512 + tid];
  if (tid < 64){ flags[tid] = isinit[b * 64 + tid]; dirty[tid] = 0; }
  __syncthreads();

  #pragma unroll 1
  for (int i = 0; i < 64; i++){
    if (!flags[i]) continue;            // uniform across block
    if (tid < 8) dirty[gall[i * 8 + tid]] = 1;

    // ---- phase A (6 waves): Zx = bias + X @ Wih^T, A-frags straight from nt16 ----
    if (!isB){
      const int ai = wsub - 1;
      const int grow = gall[i * 8 + (lr & 7)];
      h8 Af[4];
      #pragma unroll
      for (int kt = 0; kt < 4; kt++)
        Af[kt] = *(const h8*)&nt16[grow * 136 + kt * 32 + (hi << 3)];
      #pragma unroll
      for (int k = 0; k < 6; k++){
        const int ct = ai * 6 + k;
        if (ct < 16){
          f4 acc = {0.0f, 0.0f, 0.0f, 0.0f};
          #pragma unroll
          for (int kt = 0; kt < 4; kt++)
            acc = __builtin_amdgcn_mfma_f32_16x16x32_f16(Af[kt], W[k * 4 + kt], acc, 0, 0, 0);
          if (lane < 32){
            const int t0 = hi << 2, lp = ((ct & 3) << 4) + lr, g = ct >> 2;
            #pragma unroll
            for (int r = 0; r < 4; r++)
              Zx16[(((dir << 3) + t0 + r) * 64 + lp) * 4 + g] = (_Float16)(acc[r] + biasl[k]);
          }
        }
      }
    }
    __syncthreads();

    // ---- phase B (1 wave per dir): 8-step recurrence, ZERO barriers ----
    if (isB){
      float c = 0.0f;
      f4 acc[4][4];                      // [gate][ltile]; written at end of step s, read at s+1
      #pragma unroll 1
      for (int s = 0; s < 8; s++){
        const int tt = dir ? (7 - s) : s;
        uint2 zr = *(const uint2*)&Zx16[(((dir << 3) + tt) * 64 + lane) * 4];
        h2 zlo = u32_h2(zr.x), zhi2 = u32_h2(zr.y);
        float z0 = (float)zlo.x, z1 = (float)zlo.y, z2 = (float)zhi2.x, z3 = (float)zhi2.y;
        if (s > 0){
          z0 += (hi == 0 ? acc[0][0][0] : hi == 1 ? acc[0][1][0] : hi == 2 ? acc[0][2][0] : acc[0][3][0]);
          z1 += (hi == 0 ? acc[1][0][0] : hi == 1 ? acc[1][1][0] : hi == 2 ? acc[1][2][0] : acc[1][3][0]);
          z2 += (hi == 0 ? acc[2][0][0] : hi == 1 ? acc[2][1][0] : hi == 2 ? acc[2][2][0] : acc[2][3][0]);
          z3 += (hi == 0 ? acc[3][0][0] : hi == 1 ? acc[3][1][0] : hi == 2 ? acc[3][2][0] : acc[3][3][0]);
        }
        // gates (i,f,g,o); lane owns h-row l = lane
        float fi = fsig(z0);
        float ff = fsig(z1);
        float fg = ftanh(z2);
        float fo = fsig(z3);
        c = ff * c + fi * fg;
        float hn = fo * ftanh(c);
        // scatter into state mirror (row uniform across wave; one writer per element)
        nt16[gall[i * 8 + tt] * 136 + (dir << 6) + lane] = (_Float16)hn;
        if (s < 7){
          // in-register h redistribution: A-frag k = kt*32 + hi*8 + j, h[k] lives at lane k
          const int ab = hi << 5;        // 4 * (hi*8)
          float p0 = bperm_f(ab +  0, hn), p1 = bperm_f(ab +  4, hn);
          float p2 = bperm_f(ab +  8, hn), p3 = bperm_f(ab + 12, hn);
          float p4 = bperm_f(ab + 16, hn), p5 = bperm_f(ab + 20, hn);
          float p6 = bperm_f(ab + 24, hn), p7 = bperm_f(ab + 28, hn);
          float q0 = bperm_f(ab + 128, hn), q1 = bperm_f(ab + 132, hn);
          float q2 = bperm_f(ab + 136, hn), q3 = bperm_f(ab + 140, hn);
          float q4 = bperm_f(ab + 144, hn), q5 = bperm_f(ab + 148, hn);
          float q6 = bperm_f(ab + 152, hn), q7 = bperm_f(ab + 156, hn);
          h8 a0, a1;
          a0[0]=(_Float16)p0; a0[1]=(_Float16)p1; a0[2]=(_Float16)p2; a0[3]=(_Float16)p3;
          a0[4]=(_Float16)p4; a0[5]=(_Float16)p5; a0[6]=(_Float16)p6; a0[7]=(_Float16)p7;
          a1[0]=(_Float16)q0; a1[1]=(_Float16)q1; a1[2]=(_Float16)q2; a1[3]=(_Float16)q3;
          a1[4]=(_Float16)q4; a1[5]=(_Float16)q5; a1[6]=(_Float16)q6; a1[7]=(_Float16)q7;
          #pragma unroll
          for (int g = 0; g < 4; g++){
            #pragma unroll
            for (int lt = 0; lt < 4; lt++){
              f4 t = {0.0f, 0.0f, 0.0f, 0.0f};
              t = __builtin_amdgcn_mfma_f32_16x16x32_f16(a0, W[(g * 4 + lt) * 2 + 0], t, 0, 0, 0);
              t = __builtin_amdgcn_mfma_f32_16x16x32_f16(a1, W[(g * 4 + lt) * 2 + 1], t, 0, 0, 0);
              acc[g][lt] = t;
            }
          }
        }
      }
    }
    __syncthreads();
  }

  __syncthreads();
  { const float4* tf4 = (const float4*)(thoughts + (size_t)b * 8192);
    float4* of4 = (float4*)(newt + (size_t)b * 8192);
    #pragma unroll
    for (int k2 = 0; k2 < 4; k2++){
      int id4 = tid + k2 * 512;
      int row = id4 >> 5, c4 = (id4 & 31) * 4;
      float4 v = tf4[id4];
      if (dirty[row]){
        h4 hv = *(const h4*)&nt16[row * 136 + c4];
        v.x = (float)hv.x; v.y = (float)hv.y; v.z = (float)hv.z; v.w = (float)hv.w;
      }
      of4[id4] = v;
    } }
}

// ---------------- actor_2 (MFMA f16): 32 rows per block, 256 threads ----------------
// x = relu(concat(thoughts,newt)) (32x256) @ a2w1^T (256->128) + b1 -> (32x128) @ a2w2^T
// (128->64) -> tanh. f16 inputs/weights, f32 accum; no discrete decisions downstream.
__global__ __launch_bounds__(256) void k_actor2(
    const float* __restrict__ thoughts, const float* __restrict__ newt,
    const _Float16* __restrict__ w1h, const float* __restrict__ b1,
    const _Float16* __restrict__ w2h, float* __restrict__ out)
{
  const int b0 = blockIdx.x * 32;
  const int tid = threadIdx.x;
  const int w = tid >> 6, lane = tid & 63, lr = lane & 15, hi = lane >> 4;
  const int mt = w & 1, nb = (w >> 1) << 6;

  __shared__ __align__(16) _Float16 Xc[32 * 264];   // relu(concat) f16, padded (16896 B)
  __shared__ __align__(16) _Float16 Ys[32 * 136];   // hidden f16, padded (8704 B)

  #pragma unroll
  for (int k2 = 0; k2 < 8; k2++){
    int id4 = tid + k2 * 256;              // f4 index over 32 rows x 64 f4
    int row = id4 >> 6, c4 = (id4 & 63) * 4;
    const float* src = (c4 < 128) ? (thoughts + (size_t)(b0 + row) * 128 + c4)
                                  : (newt + (size_t)(b0 + row) * 128 + (c4 - 128));
    float4 v = *(const float4*)src;
    *(h4*)&Xc[row * 264 + c4] = pack_h4_relu(v);
  }
  __syncthreads();

  // GEMM1: wave (mt, nb): rows mt*16.., cols nb..nb+63
  {
    h8 Af[8];
    #pragma unroll
    for (int kt = 0; kt < 8; kt++)
      Af[kt] = *(const h8*)&Xc[(mt * 16 + lr) * 264 + kt * 32 + (hi << 3)];
    #pragma unroll
    for (int ni = 0; ni < 4; ni++){
      const int n = nb + ni * 16 + lr;
      const _Float16* wr = w1h + (size_t)n * 256 + (hi << 3);
      f4 acc = {0.0f, 0.0f, 0.0f, 0.0f};
      #pragma unroll
      for (int kt = 0; kt < 8; kt++){
        h8 bfr = *(const h8*)(wr + kt * 32);
        acc = __builtin_amdgcn_mfma_f32_16x16x32_f16(Af[kt], bfr, acc, 0, 0, 0);
      }
      const float bb = b1[n];
      #pragma unroll
      for (int r = 0; r < 4; r++){
        int row = mt * 16 + (hi << 2) + r;
        Ys[row * 136 + n] = (_Float16)(acc[r] + bb);
      }
    }
  }
  __syncthreads();

  // GEMM2: wave (mt, ni0): rows mt*16.., cols (ni0..ni0+1)*16
  {
    const int ni0 = (w >> 1) << 1;
    h8 Ag[4];
    #pragma unroll
    for (int kt = 0; kt < 4; kt++)
      Ag[kt] = *(const h8*)&Ys[(mt * 16 + lr) * 136 + kt * 32 + (hi << 3)];
    #pragma unroll
    for (int nj = 0; nj < 2; nj++){
      const int n = (ni0 + nj) * 16 + lr;
      const _Float16* wr = w2h + (size_t)n * 128 + (hi << 3);
      f4 acc = {0.0f, 0.0f, 0.0f, 0.0f};
      #pragma unroll
      for (int kt = 0; kt < 4; kt++){
        h8 bfr = *(const h8*)(wr + kt * 32);
        acc = __builtin_amdgcn_mfma_f32_16x16x32_f16(Ag[kt], bfr, acc, 0, 0, 0);
      }
      #pragma unroll
      for (int r = 0; r < 4; r++){
        int row = mt * 16 + (hi << 2) + r;
        out[(size_t)(b0 + row) * 64 + n] = ftanh(acc[r]);
      }
    }
  }
}

extern "C" void kernel_launch(void* const* d_in, const int* in_sizes, int n_in,
                              void* d_out, int out_size, void* d_ws, size_t ws_size,
                              hipStream_t stream)
{
  const float* obs  = (const float*)d_in[0];
  const float* w1   = (const float*)d_in[1];
  const float* b1   = (const float*)d_in[2];
  const float* lng  = (const float*)d_in[3];
  const float* lnb  = (const float*)d_in[4];
  const float* w2   = (const float*)d_in[5];
  const float* b2   = (const float*)d_in[6];
  const float* aw1  = (const float*)d_in[7];
  const float* ab1  = (const float*)d_in[8];
  const float* aw2  = (const float*)d_in[9];
  const float* ab2  = (const float*)d_in[10];
  const float* aw3  = (const float*)d_in[11];
  const float* ab3  = (const float*)d_in[12];
  const float* wihf = (const float*)d_in[13];
  const float* whhf = (const float*)d_in[14];
  const float* bihf = (const float*)d_in[15];
  const float* bhhf = (const float*)d_in[16];
  const float* wihb = (const float*)d_in[17];
  const float* whhb = (const float*)d_in[18];
  const float* bihb = (const float*)d_in[19];
  const float* bhhb = (const float*)d_in[20];
  const float* a2w1 = (const float*)d_in[21];
  const float* a2b1 = (const float*)d_in[22];
  const float* a2w2 = (const float*)d_in[23];

  float* thoughts = (float*)d_ws;                       // 33.5 MB
  float* newt     = thoughts + (size_t)ROWS * 128;      // 33.5 MB
  int*   isinit   = (int*)(newt + (size_t)ROWS * 128);  // 256 KB
  int*   idxb     = isinit + ROWS;                      // 2 MB
  _Float16* w1h   = (_Float16*)(idxb + (size_t)ROWS * 8);  // 64 KB
  _Float16* w2h   = w1h + 32768;                           // 16 KB

  hipLaunchKernelGGL(k_cvt, dim3(128), dim3(256), 0, stream, a2w1, a2w2, w1h, w2h);
  hipLaunchKernelGGL(k_actor1, dim3(ROWS / 8), dim3(128), 0, stream,
                     obs, w1, b1, lng, lnb, w2, b2, aw1, ab1, aw2, ab2, aw3, ab3,
                     thoughts, isinit);
  hipLaunchKernelGGL(k_groups, dim3(NB), dim3(256), 0, stream, thoughts, idxb);
  hipLaunchKernelGGL(k_scan, dim3(NB), dim3(512), 0, stream,
                     thoughts, isinit, idxb,
                     wihf, whhf, bihf, bhhf, wihb, whhb, bihb, bhhb, newt);
  hipLaunchKernelGGL(k_actor2, dim3(ROWS / 32), dim3(256), 0, stream,
                     thoughts, newt, w1h, a2b1, w2h, (float*)d_out);
}

// Round 5
// 1250.931 us; speedup vs baseline: 1.1114x; 1.1114x over previous
//
#include <hip/hip_runtime.h>

typedef unsigned int u32;
typedef unsigned short u16;
typedef unsigned long long u64;
typedef _Float16 h2 __attribute__((ext_vector_type(2)));
typedef _Float16 h4 __attribute__((ext_vector_type(4)));
typedef _Float16 h8 __attribute__((ext_vector_type(8)));
typedef float f4 __attribute__((ext_vector_type(4)));

#define ROWS 65536   // B*A
#define NB 1024
#define NA 64

__device__ __forceinline__ float dot4(float4 w, float4 x){
  return w.x*x.x + w.y*x.y + w.z*x.z + w.w*x.w;
}
__device__ __forceinline__ h2 u32_h2(u32 v){ union { u32 u; h2 h; } x; x.u = v; return x.h; }
__device__ __forceinline__ h2 pack_h2(float a, float b){ h2 r; r.x = (_Float16)a; r.y = (_Float16)b; return r; }
__device__ __forceinline__ h4 pack_h4(float4 v){
  h4 r; r.x=(_Float16)v.x; r.y=(_Float16)v.y; r.z=(_Float16)v.z; r.w=(_Float16)v.w; return r;
}
__device__ __forceinline__ h4 pack_h4_relu(float4 v){
  h4 r; r.x=(_Float16)fmaxf(v.x,0.f); r.y=(_Float16)fmaxf(v.y,0.f);
  r.z=(_Float16)fmaxf(v.z,0.f); r.w=(_Float16)fmaxf(v.w,0.f); return r;
}
// fast sigmoid/tanh on v_exp_f32 + v_rcp_f32 (~1 ulp each; threshold is 1.1e-2)
__device__ __forceinline__ float fsig(float z){
  float e = __builtin_amdgcn_exp2f(-1.44269504f * z);
  return __builtin_amdgcn_rcpf(1.0f + e);
}
__device__ __forceinline__ float ftanh(float z){
  float e = __builtin_amdgcn_exp2f(2.885390082f * z);
  return 1.0f - 2.0f * __builtin_amdgcn_rcpf(1.0f + e);
}
__device__ __forceinline__ h8 load8f(const float* p){
  float4 a = *(const float4*)p;
  float4 b = *(const float4*)(p + 4);
  h8 r;
  r[0] = (_Float16)a.x; r[1] = (_Float16)a.y; r[2] = (_Float16)a.z; r[3] = (_Float16)a.w;
  r[4] = (_Float16)b.x; r[5] = (_Float16)b.y; r[6] = (_Float16)b.z; r[7] = (_Float16)b.w;
  return r;
}
__device__ __forceinline__ float bperm_f(int addr, float v){
  return __int_as_float(__builtin_amdgcn_ds_bpermute(addr, __float_as_int(v)));
}

// ---------------- weight f16 pre-convert (actor_2 weights) ----------------
__global__ __launch_bounds__(256) void k_cvt(
    const float* __restrict__ a2w1, const float* __restrict__ a2w2,
    _Float16* __restrict__ w1h, _Float16* __restrict__ w2h)
{
  int i = blockIdx.x * 256 + threadIdx.x;
  if (i < 32768) w1h[i] = (_Float16)a2w1[i];
  if (i < 8192)  w2h[i] = (_Float16)a2w2[i];
}

// ---------------- actor_1 + attention: 8 rows per block, 128 threads ----------------
// kept f32/VALU: feeds the DISCRETE decisions (isinit threshold, K-nearest argsort) where
// f16 rounding (~1e-3) could flip group membership and blow up absmax.
__global__ __launch_bounds__(128) void k_actor1(
    const float* __restrict__ obs, const float* __restrict__ w1, const float* __restrict__ b1,
    const float* __restrict__ lng, const float* __restrict__ lnb,
    const float* __restrict__ w2, const float* __restrict__ b2,
    const float* __restrict__ aw1, const float* __restrict__ ab1,
    const float* __restrict__ aw2, const float* __restrict__ ab2,
    const float* __restrict__ aw3, const float* __restrict__ ab3,
    float* __restrict__ thoughts, int* __restrict__ isinit)
{
  const int b0 = blockIdx.x * 8;
  const int t = threadIdx.x;
  __shared__ float4 xs[8][64];     // 8 obs rows (256 f32 each)
  __shared__ float hs[8][128];     // relu(LN(h))
  __shared__ float tb[8][128];     // thoughts
  __shared__ float ab[8][64];
  __shared__ float a2b[8][64];
  __shared__ float red[8][4];

  { const float4* og = (const float4*)(obs + (size_t)b0 * 256);
    #pragma unroll
    for (int j = 0; j < 4; j++){ int p = j * 128 + t; xs[p >> 6][p & 63] = og[p]; } }
  __syncthreads();

  // h = obs @ W1^T + b1   (thread t owns output feature t, streams W1 row t)
  float acc[8];
  #pragma unroll
  for (int r = 0; r < 8; r++) acc[r] = b1[t];
  { const float4* wr = (const float4*)(w1 + (size_t)t * 256);
    for (int j = 0; j < 64; j++){
      float4 w = wr[j];
      #pragma unroll
      for (int r = 0; r < 8; r++) acc[r] += dot4(w, xs[r][j]);
    } }

  // LayerNorm over 128 features (block = 2 waves)
  #pragma unroll
  for (int r = 0; r < 8; r++){
    float s = acc[r], s2 = acc[r] * acc[r];
    #pragma unroll
    for (int off = 32; off > 0; off >>= 1){ s += __shfl_down(s, off); s2 += __shfl_down(s2, off); }
    if ((t & 63) == 0){ red[r][t >> 6] = s; red[r][2 + (t >> 6)] = s2; }
  }
  __syncthreads();
  const float g_ = lng[t], bb_ = lnb[t];
  #pragma unroll
  for (int r = 0; r < 8; r++){
    float mu  = (red[r][0] + red[r][1]) * (1.0f/128.0f);
    float var = (red[r][2] + red[r][3]) * (1.0f/128.0f) - mu * mu;
    hs[r][t] = fmaxf((acc[r] - mu) * rsqrtf(var + 1e-5f) * g_ + bb_, 0.0f);
  }
  __syncthreads();

  // thoughts = relu(h) @ W2^T + b2
  float acc2[8];
  #pragma unroll
  for (int r = 0; r < 8; r++) acc2[r] = b2[t];
  { const float4* wr = (const float4*)(w2 + (size_t)t * 128);
    for (int j = 0; j < 32; j++){
      float4 w = wr[j];
      #pragma unroll
      for (int r = 0; r < 8; r++) acc2[r] += dot4(w, ((const float4*)hs[r])[j]);
    } }
  #pragma unroll
  for (int r = 0; r < 8; r++){
    thoughts[(size_t)(b0 + r) * 128 + t] = acc2[r];
    tb[r][t] = acc2[r];
  }
  __syncthreads();

  // attention MLP
  if (t < 64){
    float a[8];
    #pragma unroll
    for (int r = 0; r < 8; r++) a[r] = ab1[t];
    const float4* wr = (const float4*)(aw1 + (size_t)t * 128);
    for (int j = 0; j < 32; j++){
      float4 w = wr[j];
      #pragma unroll
      for (int r = 0; r < 8; r++) a[r] += dot4(w, ((const float4*)tb[r])[j]);
    }
    #pragma unroll
    for (int r = 0; r < 8; r++) ab[r][t] = fmaxf(a[r], 0.0f);
  }
  __syncthreads();
  if (t < 64){
    float a[8];
    #pragma unroll
    for (int r = 0; r < 8; r++) a[r] = ab2[t];
    const float4* wr = (const float4*)(aw2 + (size_t)t * 64);
    for (int j = 0; j < 16; j++){
      float4 w = wr[j];
      #pragma unroll
      for (int r = 0; r < 8; r++) a[r] += dot4(w, ((const float4*)ab[r])[j]);
    }
    #pragma unroll
    for (int r = 0; r < 8; r++) a2b[r][t] = fmaxf(a[r], 0.0f);
  }
  __syncthreads();
  if (t < 8){
    float p = ab3[0];
    for (int j = 0; j < 64; j++) p += aw3[j] * a2b[t][j];
    isinit[b0 + t] = (p > 0.0f) ? 1 : 0;   // sigmoid(p) > 0.5  <=>  p > 0
  }
}

// ---------------- K-nearest groups: one block per batch ----------------
__global__ __launch_bounds__(256) void k_groups(
    const float* __restrict__ thoughts, int* __restrict__ idxout)
{
  const int b = blockIdx.x;
  const int tid = threadIdx.x;
  __shared__ float T[64 * 130];
  __shared__ float sq[64];
  for (int p = tid; p < 8192; p += 256){
    T[(p >> 7) * 130 + (p & 127)] = thoughts[(size_t)b * 8192 + p];
  }
  __syncthreads();
  if (tid < 64){
    const float2* tj = (const float2*)&T[tid * 130];
    float s = 0.0f;
    #pragma unroll 8
    for (int k = 0; k < 64; k++){ float2 v = tj[k]; s += v.x*v.x + v.y*v.y; }
    sq[tid] = s;
  }
  __syncthreads();
  const int lane = tid & 63;
  const int wv = tid >> 6;
  const float2* tj = (const float2*)&T[lane * 130];
  const float sqj = sq[lane];
  for (int ii = 0; ii < 16; ii++){
    const int i = wv * 16 + ii;
    const float2* ti = (const float2*)&T[i * 130];
    float dot = 0.0f;
    #pragma unroll 8
    for (int k = 0; k < 64; k++){ float2 a = ti[k]; float2 c = tj[k]; dot += a.x*c.x + a.y*c.y; }
    float d = fmaxf(sq[i] + sqj - 2.0f*dot, 0.0f);   // clamp keeps uint-compare == float-compare
    u64 key = (((u64)__float_as_uint(d)) << 32) | (u32)lane;
    u64 mask = 0;
    for (int q = 0; q < 8; q++){
      u64 m = key;
      #pragma unroll
      for (int off = 32; off > 0; off >>= 1){ u64 o = __shfl_xor(m, off); if (o < m) m = o; }
      mask |= 1ull << (u32)(m & 63u);
      if (key == m) key = ~0ull;
    }
    if (lane == 0){
      u64 mm = mask;
      int base = (b * 64 + i) * 8;
      #pragma unroll
      for (int q = 0; q < 8; q++){ int j = (int)__builtin_ctzll(mm); mm &= mm - 1; idxout[base + q] = j; }
    }
  }
}

// ---------------- sequential gather -> bi-LSTM -> scatter: one block per batch ----------------
// v6 = v5 (barrier-free recurrence, proven correct in r4) with the register economics fixed:
// (a) __launch_bounds__(512, 2): 2 waves/EU = exactly 1 block/CU -> VGPR cap 256 (was 128,
//     which spilled W[32]+acc to scratch: +63 MB/dispatch scratch traffic, 850 us).
// (b) phase B immediate-consume: each tile's MFMA result folds into z[g] via the hi==lt
//     select right away; no persistent acc[4][4] (-64 VGPR). Peak demand ~170 < 256.
// Waves 0 (fwd) / 4 (bwd) own the entire 8-step recurrence: lane l computes gates/c/hn for
// h-row l; h redistributes to the MFMA A-fragment layout in-register via 16 ds_bpermute.
// Phase A (Zx = bias + X @ Wih^T) on the other 6 waves (coltiles split {6,6,4}).
// Barriers per initiator: 2 (was 9 in v4). MFMA conventions (verified v3/v4/v5):
// A row = lane&15, B col = lane&15, k = kt*32+(lane>>4)*8+j, C: col=lane&15, row=(lane>>4)*4+reg.
__global__ __launch_bounds__(512, 2) void k_scan(
    const float* __restrict__ thoughts, const int* __restrict__ isinit, const int* __restrict__ idx,
    const float* __restrict__ wihf, const float* __restrict__ whhf,
    const float* __restrict__ bihf, const float* __restrict__ bhhf,
    const float* __restrict__ wihb, const float* __restrict__ whhb,
    const float* __restrict__ bihb, const float* __restrict__ bhhb,
    float* __restrict__ newt)
{
  const int b    = blockIdx.x;
  const int tid  = threadIdx.x;
  const int w    = tid >> 6;          // wave 0..7
  const int lane = tid & 63;
  const int dir  = w >> 2;            // waves 0-3 fwd, 4-7 bwd
  const int wsub = w & 3;             // 0 -> recurrence wave; 1..3 -> phase-A waves
  const int lr   = lane & 15;
  const int hi   = lane >> 4;
  const bool isB = (wsub == 0);

  __shared__ __align__(16) _Float16 nt16[64 * 136];  // f16 state mirror, padded (17408 B)
  __shared__ __align__(16) _Float16 Zx16[2*8*64*4];  // input projection (+bias), f16 (8192 B)
  __shared__ int gall[512];
  __shared__ int flags[64];
  __shared__ int dirty[64];

  const float* wih = dir ? wihb : wihf;
  const float* whh = dir ? whhb : whhf;

  // ---- weight fragments (register union) ----
  // A-waves (wsub 1..3): W[k*4+kt] = Wih coltile (ai*6+k), kt<4   (<=96 VGPR)
  // B-waves (wsub == 0): W[ct*2+kt] = Whh coltile ct, kt<2        (128 VGPR)
  h8 W[32];
  float biasl[6];
  if (isB){
    #pragma unroll
    for (int ct = 0; ct < 16; ct++){
      const int n = ((ct >> 2) << 6) + ((ct & 3) << 4) + lr;
      const float* wr = whh + (size_t)n * 64 + (hi << 3);
      W[ct * 2 + 0] = load8f(wr);
      W[ct * 2 + 1] = load8f(wr + 32);
      __builtin_amdgcn_sched_barrier(0);
    }
  } else {
    const int ai = wsub - 1;
    const float* bih = dir ? bihb : bihf;
    const float* bhh = dir ? bhhb : bhhf;
    #pragma unroll
    for (int k = 0; k < 6; k++){
      const int ct = ai * 6 + k;
      if (ct < 16){
        const int n = ((ct >> 2) << 6) + ((ct & 3) << 4) + lr;
        const float* wr = wih + (size_t)n * 128 + (hi << 3);
        #pragma unroll
        for (int kt = 0; kt < 4; kt++) W[k * 4 + kt] = load8f(wr + kt * 32);
        biasl[k] = bih[n] + bhh[n];
      }
      __builtin_amdgcn_sched_barrier(0);
    }
  }

  { const float4* tf4 = (const float4*)(thoughts + (size_t)b * 8192);
    #pragma unroll
    for (int k2 = 0; k2 < 4; k2++){
      int id4 = tid + k2 * 512;                 // f4 index, 2048 total (32 f4 per row)
      float4 v = tf4[id4];
      *(h4*)&nt16[(id4 >> 5) * 136 + (id4 & 31) * 4] = pack_h4(v);
    } }
  gall[tid] = idx[(size_t)b * 512 + tid];
  if (tid < 64){ flags[tid] = isinit[b * 64 + tid]; dirty[tid] = 0; }
  __syncthreads();

  #pragma unroll 1
  for (int i = 0; i < 64; i++){
    if (!flags[i]) continue;            // uniform across block
    if (tid < 8) dirty[gall[i * 8 + tid]] = 1;

    // ---- phase A (6 waves): Zx = bias + X @ Wih^T, A-frags straight from nt16 ----
    if (!isB){
      const int ai = wsub - 1;
      const int grow = gall[i * 8 + (lr & 7)];
      h8 Af[4];
      #pragma unroll
      for (int kt = 0; kt < 4; kt++)
        Af[kt] = *(const h8*)&nt16[grow * 136 + kt * 32 + (hi << 3)];
      #pragma unroll
      for (int k = 0; k < 6; k++){
        const int ct = ai * 6 + k;
        if (ct < 16){
          f4 acc = {0.0f, 0.0f, 0.0f, 0.0f};
          #pragma unroll
          for (int kt = 0; kt < 4; kt++)
            acc = __builtin_amdgcn_mfma_f32_16x16x32_f16(Af[kt], W[k * 4 + kt], acc, 0, 0, 0);
          if (lane < 32){
            const int t0 = hi << 2, lp = ((ct & 3) << 4) + lr, g = ct >> 2;
            #pragma unroll
            for (int r = 0; r < 4; r++)
              Zx16[(((dir << 3) + t0 + r) * 64 + lp) * 4 + g] = (_Float16)(acc[r] + biasl[k]);
          }
        }
      }
    }
    __syncthreads();

    // ---- phase B (1 wave per dir): 8-step recurrence, ZERO barriers ----
    if (isB){
      float c = 0.0f;
      h8 a0 = {}, a1 = {};               // h in A-fragment layout (set at end of each step)
      #pragma unroll 1
      for (int s = 0; s < 8; s++){
        const int tt = dir ? (7 - s) : s;
        uint2 zr = *(const uint2*)&Zx16[(((dir << 3) + tt) * 64 + lane) * 4];
        h2 zlo = u32_h2(zr.x), zhi2 = u32_h2(zr.y);
        float z0 = (float)zlo.x, z1 = (float)zlo.y, z2 = (float)zhi2.x, z3 = (float)zhi2.y;
        if (s > 0){
          // 16 tiles; each result consumed immediately into a scalar (no persistent acc[][])
          float za[4];
          #pragma unroll
          for (int g = 0; g < 4; g++){
            float zs = 0.0f;
            #pragma unroll
            for (int lt = 0; lt < 4; lt++){
              f4 t = {0.0f, 0.0f, 0.0f, 0.0f};
              t = __builtin_amdgcn_mfma_f32_16x16x32_f16(a0, W[(g * 4 + lt) * 2 + 0], t, 0, 0, 0);
              t = __builtin_amdgcn_mfma_f32_16x16x32_f16(a1, W[(g * 4 + lt) * 2 + 1], t, 0, 0, 0);
              zs = (hi == lt) ? t[0] : zs;
            }
            za[g] = zs;
          }
          z0 += za[0]; z1 += za[1]; z2 += za[2]; z3 += za[3];
        }
        // gates (i,f,g,o); lane owns h-row l = lane
        float fi = fsig(z0);
        float ff = fsig(z1);
        float fg = ftanh(z2);
        float fo = fsig(z3);
        c = ff * c + fi * fg;
        float hn = fo * ftanh(c);
        // scatter into state mirror (row uniform across wave; one writer per element)
        nt16[gall[i * 8 + tt] * 136 + (dir << 6) + lane] = (_Float16)hn;
        if (s < 7){
          // in-register h redistribution: A-frag k = kt*32 + hi*8 + j, h[k] lives at lane k
          const int ab = hi << 5;        // 4 * (hi*8)
          float p0 = bperm_f(ab +  0, hn), p1 = bperm_f(ab +  4, hn);
          float p2 = bperm_f(ab +  8, hn), p3 = bperm_f(ab + 12, hn);
          float p4 = bperm_f(ab + 16, hn), p5 = bperm_f(ab + 20, hn);
          float p6 = bperm_f(ab + 24, hn), p7 = bperm_f(ab + 28, hn);
          float q0 = bperm_f(ab + 128, hn), q1 = bperm_f(ab + 132, hn);
          float q2 = bperm_f(ab + 136, hn), q3 = bperm_f(ab + 140, hn);
          float q4 = bperm_f(ab + 144, hn), q5 = bperm_f(ab + 148, hn);
          float q6 = bperm_f(ab + 152, hn), q7 = bperm_f(ab + 156, hn);
          a0[0]=(_Float16)p0; a0[1]=(_Float16)p1; a0[2]=(_Float16)p2; a0[3]=(_Float16)p3;
          a0[4]=(_Float16)p4; a0[5]=(_Float16)p5; a0[6]=(_Float16)p6; a0[7]=(_Float16)p7;
          a1[0]=(_Float16)q0; a1[1]=(_Float16)q1; a1[2]=(_Float16)q2; a1[3]=(_Float16)q3;
          a1[4]=(_Float16)q4; a1[5]=(_Float16)q5; a1[6]=(_Float16)q6; a1[7]=(_Float16)q7;
        }
      }
    }
    __syncthreads();
  }

  __syncthreads();
  { const float4* tf4 = (const float4*)(thoughts + (size_t)b * 8192);
    float4* of4 = (float4*)(newt + (size_t)b * 8192);
    #pragma unroll
    for (int k2 = 0; k2 < 4; k2++){
      int id4 = tid + k2 * 512;
      int row = id4 >> 5, c4 = (id4 & 31) * 4;
      float4 v = tf4[id4];
      if (dirty[row]){
        h4 hv = *(const h4*)&nt16[row * 136 + c4];
        v.x = (float)hv.x; v.y = (float)hv.y; v.z = (float)hv.z; v.w = (float)hv.w;
      }
      of4[id4] = v;
    } }
}

// ---------------- actor_2 (MFMA f16): 32 rows per block, 256 threads ----------------
// x = relu(concat(thoughts,newt)) (32x256) @ a2w1^T (256->128) + b1 -> (32x128) @ a2w2^T
// (128->64) -> tanh. f16 inputs/weights, f32 accum; no discrete decisions downstream.
__global__ __launch_bounds__(256) void k_actor2(
    const float* __restrict__ thoughts, const float* __restrict__ newt,
    const _Float16* __restrict__ w1h, const float* __restrict__ b1,
    const _Float16* __restrict__ w2h, float* __restrict__ out)
{
  const int b0 = blockIdx.x * 32;
  const int tid = threadIdx.x;
  const int w = tid >> 6, lane = tid & 63, lr = lane & 15, hi = lane >> 4;
  const int mt = w & 1, nb = (w >> 1) << 6;

  __shared__ __align__(16) _Float16 Xc[32 * 264];   // relu(concat) f16, padded (16896 B)
  __shared__ __align__(16) _Float16 Ys[32 * 136];   // hidden f16, padded (8704 B)

  #pragma unroll
  for (int k2 = 0; k2 < 8; k2++){
    int id4 = tid + k2 * 256;              // f4 index over 32 rows x 64 f4
    int row = id4 >> 6, c4 = (id4 & 63) * 4;
    const float* src = (c4 < 128) ? (thoughts + (size_t)(b0 + row) * 128 + c4)
                                  : (newt + (size_t)(b0 + row) * 128 + (c4 - 128));
    float4 v = *(const float4*)src;
    *(h4*)&Xc[row * 264 + c4] = pack_h4_relu(v);
  }
  __syncthreads();

  // GEMM1: wave (mt, nb): rows mt*16.., cols nb..nb+63
  {
    h8 Af[8];
    #pragma unroll
    for (int kt = 0; kt < 8; kt++)
      Af[kt] = *(const h8*)&Xc[(mt * 16 + lr) * 264 + kt * 32 + (hi << 3)];
    #pragma unroll
    for (int ni = 0; ni < 4; ni++){
      const int n = nb + ni * 16 + lr;
      const _Float16* wr = w1h + (size_t)n * 256 + (hi << 3);
      f4 acc = {0.0f, 0.0f, 0.0f, 0.0f};
      #pragma unroll
      for (int kt = 0; kt < 8; kt++){
        h8 bfr = *(const h8*)(wr + kt * 32);
        acc = __builtin_amdgcn_mfma_f32_16x16x32_f16(Af[kt], bfr, acc, 0, 0, 0);
      }
      const float bb = b1[n];
      #pragma unroll
      for (int r = 0; r < 4; r++){
        int row = mt * 16 + (hi << 2) + r;
        Ys[row * 136 + n] = (_Float16)(acc[r] + bb);
      }
    }
  }
  __syncthreads();

  // GEMM2: wave (mt, ni0): rows mt*16.., cols (ni0..ni0+1)*16
  {
    const int ni0 = (w >> 1) << 1;
    h8 Ag[4];
    #pragma unroll
    for (int kt = 0; kt < 4; kt++)
      Ag[kt] = *(const h8*)&Ys[(mt * 16 + lr) * 136 + kt * 32 + (hi << 3)];
    #pragma unroll
    for (int nj = 0; nj < 2; nj++){
      const int n = (ni0 + nj) * 16 + lr;
      const _Float16* wr = w2h + (size_t)n * 128 + (hi << 3);
      f4 acc = {0.0f, 0.0f, 0.0f, 0.0f};
      #pragma unroll
      for (int kt = 0; kt < 4; kt++){
        h8 bfr = *(const h8*)(wr + kt * 32);
        acc = __builtin_amdgcn_mfma_f32_16x16x32_f16(Ag[kt], bfr, acc, 0, 0, 0);
      }
      #pragma unroll
      for (int r = 0; r < 4; r++){
        int row = mt * 16 + (hi << 2) + r;
        out[(size_t)(b0 + row) * 64 + n] = ftanh(acc[r]);
      }
    }
  }
}

extern "C" void kernel_launch(void* const* d_in, const int* in_sizes, int n_in,
                              void* d_out, int out_size, void* d_ws, size_t ws_size,
                              hipStream_t stream)
{
  const float* obs  = (const float*)d_in[0];
  const float* w1   = (const float*)d_in[1];
  const float* b1   = (const float*)d_in[2];
  const float* lng  = (const float*)d_in[3];
  const float* lnb  = (const float*)d_in[4];
  const float* w2   = (const float*)d_in[5];
  const float* b2   = (const float*)d_in[6];
  const float* aw1  = (const float*)d_in[7];
  const float* ab1  = (const float*)d_in[8];
  const float* aw2  = (const float*)d_in[9];
  const float* ab2  = (const float*)d_in[10];
  const float* aw3  = (const float*)d_in[11];
  const float* ab3  = (const float*)d_in[12];
  const float* wihf = (const float*)d_in[13];
  const float* whhf = (const float*)d_in[14];
  const float* bihf = (const float*)d_in[15];
  const float* bhhf = (const float*)d_in[16];
  const float* wihb = (const float*)d_in[17];
  const float* whhb = (const float*)d_in[18];
  const float* bihb = (const float*)d_in[19];
  const float* bhhb = (const float*)d_in[20];
  const float* a2w1 = (const float*)d_in[21];
  const float* a2b1 = (const float*)d_in[22];
  const float* a2w2 = (const float*)d_in[23];

  float* thoughts = (float*)d_ws;                       // 33.5 MB
  float* newt     = thoughts + (size_t)ROWS * 128;      // 33.5 MB
  int*   isinit   = (int*)(newt + (size_t)ROWS * 128);  // 256 KB
  int*   idxb     = isinit + ROWS;                      // 2 MB
  _Float16* w1h   = (_Float16*)(idxb + (size_t)ROWS * 8);  // 64 KB
  _Float16* w2h   = w1h + 32768;                           // 16 KB

  hipLaunchKernelGGL(k_cvt, dim3(128), dim3(256), 0, stream, a2w1, a2w2, w1h, w2h);
  hipLaunchKernelGGL(k_actor1, dim3(ROWS / 8), dim3(128), 0, stream,
                     obs, w1, b1, lng, lnb, w2, b2, aw1, ab1, aw2, ab2, aw3, ab3,
                     thoughts, isinit);
  hipLaunchKernelGGL(k_groups, dim3(NB), dim3(256), 0, stream, thoughts, idxb);
  hipLaunchKernelGGL(k_scan, dim3(NB), dim3(512), 0, stream,
                     thoughts, isinit, idxb,
                     wihf, whhf, bihf, bhhf, wihb, whhb, bihb, bhhb, newt);
  hipLaunchKernelGGL(k_actor2, dim3(ROWS / 32), dim3(256), 0, stream,
                     thoughts, newt, w1h, a2b1, w2h, (float*)d_out);
}

// Round 6
// 955.722 us; speedup vs baseline: 1.4548x; 1.3089x over previous
//
#include <hip/hip_runtime.h>

typedef unsigned int u32;
typedef unsigned short u16;
typedef unsigned long long u64;
typedef _Float16 h2 __attribute__((ext_vector_type(2)));
typedef _Float16 h4 __attribute__((ext_vector_type(4)));
typedef _Float16 h8 __attribute__((ext_vector_type(8)));
typedef float f4 __attribute__((ext_vector_type(4)));

#define ROWS 65536   // B*A
#define NB 1024
#define NA 64

__device__ __forceinline__ float dot4(float4 w, float4 x){
  return w.x*x.x + w.y*x.y + w.z*x.z + w.w*x.w;
}
__device__ __forceinline__ h2 u32_h2(u32 v){ union { u32 u; h2 h; } x; x.u = v; return x.h; }
__device__ __forceinline__ h2 pack_h2(float a, float b){ h2 r; r.x = (_Float16)a; r.y = (_Float16)b; return r; }
__device__ __forceinline__ h4 pack_h4(float4 v){
  h4 r; r.x=(_Float16)v.x; r.y=(_Float16)v.y; r.z=(_Float16)v.z; r.w=(_Float16)v.w; return r;
}
__device__ __forceinline__ h4 pack_h4_relu(float4 v){
  h4 r; r.x=(_Float16)fmaxf(v.x,0.f); r.y=(_Float16)fmaxf(v.y,0.f);
  r.z=(_Float16)fmaxf(v.z,0.f); r.w=(_Float16)fmaxf(v.w,0.f); return r;
}
// fast sigmoid/tanh on v_exp_f32 + v_rcp_f32 (~1 ulp each; threshold is 1.1e-2)
__device__ __forceinline__ float fsig(float z){
  float e = __builtin_amdgcn_exp2f(-1.44269504f * z);
  return __builtin_amdgcn_rcpf(1.0f + e);
}
__device__ __forceinline__ float ftanh(float z){
  float e = __builtin_amdgcn_exp2f(2.885390082f * z);
  return 1.0f - 2.0f * __builtin_amdgcn_rcpf(1.0f + e);
}
__device__ __forceinline__ h8 load8f(const float* p){
  float4 a = *(const float4*)p;
  float4 b = *(const float4*)(p + 4);
  h8 r;
  r[0] = (_Float16)a.x; r[1] = (_Float16)a.y; r[2] = (_Float16)a.z; r[3] = (_Float16)a.w;
  r[4] = (_Float16)b.x; r[5] = (_Float16)b.y; r[6] = (_Float16)b.z; r[7] = (_Float16)b.w;
  return r;
}

// ---------------- weight f16 pre-convert (actor_2 weights) ----------------
__global__ __launch_bounds__(256) void k_cvt(
    const float* __restrict__ a2w1, const float* __restrict__ a2w2,
    _Float16* __restrict__ w1h, _Float16* __restrict__ w2h)
{
  int i = blockIdx.x * 256 + threadIdx.x;
  if (i < 32768) w1h[i] = (_Float16)a2w1[i];
  if (i < 8192)  w2h[i] = (_Float16)a2w2[i];
}

// ---------------- actor_1 + attention: 8 rows per block, 128 threads ----------------
// kept f32/VALU: feeds the DISCRETE decisions (isinit threshold, K-nearest argsort) where
// f16 rounding (~1e-3) could flip group membership and blow up absmax.
__global__ __launch_bounds__(128) void k_actor1(
    const float* __restrict__ obs, const float* __restrict__ w1, const float* __restrict__ b1,
    const float* __restrict__ lng, const float* __restrict__ lnb,
    const float* __restrict__ w2, const float* __restrict__ b2,
    const float* __restrict__ aw1, const float* __restrict__ ab1,
    const float* __restrict__ aw2, const float* __restrict__ ab2,
    const float* __restrict__ aw3, const float* __restrict__ ab3,
    float* __restrict__ thoughts, int* __restrict__ isinit)
{
  const int b0 = blockIdx.x * 8;
  const int t = threadIdx.x;
  __shared__ float4 xs[8][64];     // 8 obs rows (256 f32 each)
  __shared__ float hs[8][128];     // relu(LN(h))
  __shared__ float tb[8][128];     // thoughts
  __shared__ float ab[8][64];
  __shared__ float a2b[8][64];
  __shared__ float red[8][4];

  { const float4* og = (const float4*)(obs + (size_t)b0 * 256);
    #pragma unroll
    for (int j = 0; j < 4; j++){ int p = j * 128 + t; xs[p >> 6][p & 63] = og[p]; } }
  __syncthreads();

  // h = obs @ W1^T + b1   (thread t owns output feature t, streams W1 row t)
  float acc[8];
  #pragma unroll
  for (int r = 0; r < 8; r++) acc[r] = b1[t];
  { const float4* wr = (const float4*)(w1 + (size_t)t * 256);
    for (int j = 0; j < 64; j++){
      float4 w = wr[j];
      #pragma unroll
      for (int r = 0; r < 8; r++) acc[r] += dot4(w, xs[r][j]);
    } }

  // LayerNorm over 128 features (block = 2 waves)
  #pragma unroll
  for (int r = 0; r < 8; r++){
    float s = acc[r], s2 = acc[r] * acc[r];
    #pragma unroll
    for (int off = 32; off > 0; off >>= 1){ s += __shfl_down(s, off); s2 += __shfl_down(s2, off); }
    if ((t & 63) == 0){ red[r][t >> 6] = s; red[r][2 + (t >> 6)] = s2; }
  }
  __syncthreads();
  const float g_ = lng[t], bb_ = lnb[t];
  #pragma unroll
  for (int r = 0; r < 8; r++){
    float mu  = (red[r][0] + red[r][1]) * (1.0f/128.0f);
    float var = (red[r][2] + red[r][3]) * (1.0f/128.0f) - mu * mu;
    hs[r][t] = fmaxf((acc[r] - mu) * rsqrtf(var + 1e-5f) * g_ + bb_, 0.0f);
  }
  __syncthreads();

  // thoughts = relu(h) @ W2^T + b2
  float acc2[8];
  #pragma unroll
  for (int r = 0; r < 8; r++) acc2[r] = b2[t];
  { const float4* wr = (const float4*)(w2 + (size_t)t * 128);
    for (int j = 0; j < 32; j++){
      float4 w = wr[j];
      #pragma unroll
      for (int r = 0; r < 8; r++) acc2[r] += dot4(w, ((const float4*)hs[r])[j]);
    } }
  #pragma unroll
  for (int r = 0; r < 8; r++){
    thoughts[(size_t)(b0 + r) * 128 + t] = acc2[r];
    tb[r][t] = acc2[r];
  }
  __syncthreads();

  // attention MLP
  if (t < 64){
    float a[8];
    #pragma unroll
    for (int r = 0; r < 8; r++) a[r] = ab1[t];
    const float4* wr = (const float4*)(aw1 + (size_t)t * 128);
    for (int j = 0; j < 32; j++){
      float4 w = wr[j];
      #pragma unroll
      for (int r = 0; r < 8; r++) a[r] += dot4(w, ((const float4*)tb[r])[j]);
    }
    #pragma unroll
    for (int r = 0; r < 8; r++) ab[r][t] = fmaxf(a[r], 0.0f);
  }
  __syncthreads();
  if (t < 64){
    float a[8];
    #pragma unroll
    for (int r = 0; r < 8; r++) a[r] = ab2[t];
    const float4* wr = (const float4*)(aw2 + (size_t)t * 64);
    for (int j = 0; j < 16; j++){
      float4 w = wr[j];
      #pragma unroll
      for (int r = 0; r < 8; r++) a[r] += dot4(w, ((const float4*)ab[r])[j]);
    }
    #pragma unroll
    for (int r = 0; r < 8; r++) a2b[r][t] = fmaxf(a[r], 0.0f);
  }
  __syncthreads();
  if (t < 8){
    float p = ab3[0];
    for (int j = 0; j < 64; j++) p += aw3[j] * a2b[t][j];
    isinit[b0 + t] = (p > 0.0f) ? 1 : 0;   // sigmoid(p) > 0.5  <=>  p > 0
  }
}

// ---------------- K-nearest groups: one block per batch ----------------
__global__ __launch_bounds__(256) void k_groups(
    const float* __restrict__ thoughts, int* __restrict__ idxout)
{
  const int b = blockIdx.x;
  const int tid = threadIdx.x;
  __shared__ float T[64 * 130];
  __shared__ float sq[64];
  for (int p = tid; p < 8192; p += 256){
    T[(p >> 7) * 130 + (p & 127)] = thoughts[(size_t)b * 8192 + p];
  }
  __syncthreads();
  if (tid < 64){
    const float2* tj = (const float2*)&T[tid * 130];
    float s = 0.0f;
    #pragma unroll 8
    for (int k = 0; k < 64; k++){ float2 v = tj[k]; s += v.x*v.x + v.y*v.y; }
    sq[tid] = s;
  }
  __syncthreads();
  const int lane = tid & 63;
  const int wv = tid >> 6;
  const float2* tj = (const float2*)&T[lane * 130];
  const float sqj = sq[lane];
  for (int ii = 0; ii < 16; ii++){
    const int i = wv * 16 + ii;
    const float2* ti = (const float2*)&T[i * 130];
    float dot = 0.0f;
    #pragma unroll 8
    for (int k = 0; k < 64; k++){ float2 a = ti[k]; float2 c = tj[k]; dot += a.x*c.x + a.y*c.y; }
    float d = fmaxf(sq[i] + sqj - 2.0f*dot, 0.0f);   // clamp keeps uint-compare == float-compare
    u64 key = (((u64)__float_as_uint(d)) << 32) | (u32)lane;
    u64 mask = 0;
    for (int q = 0; q < 8; q++){
      u64 m = key;
      #pragma unroll
      for (int off = 32; off > 0; off >>= 1){ u64 o = __shfl_xor(m, off); if (o < m) m = o; }
      mask |= 1ull << (u32)(m & 63u);
      if (key == m) key = ~0ull;
    }
    if (lane == 0){
      u64 mm = mask;
      int base = (b * 64 + i) * 8;
      #pragma unroll
      for (int q = 0; q < 8; q++){ int j = (int)__builtin_ctzll(mm); mm &= mm - 1; idxout[base + q] = j; }
    }
  }
}

// ---------------- sequential gather -> bi-LSTM -> scatter: TWO batches per block ----------------
// v7 = v4 skeleton (8-wave phase split, 2 blocks/CU) packing 2 batches per block:
//  * phase A: A rows 0-7 = batch0 X, rows 8-15 = batch1 X (the rows v4 wasted on duplicates
//    now carry batch1) -> per-batch phase-A MFMA cost HALVED. C rows 0-7/8-15 -> Zx[0]/Zx[1].
//  * phase B: v4 dup-trick per wave (dir, l-slice=wsub), run per batch with the SAME Bh
//    registers (weights batch-independent); per-gate-sequential MFMA caps transients.
//  * 4 independent serial chains per CU (2 blocks x 2 batches, was 2) hide the barrier
//    intervals that bound v2-v4 at ~470 us; 512 blocks = ONE occupancy round (was 2).
// Barriers unconditional when (f0|f1) (block-uniform); inactive batch's work guarded off.
// MFMA conventions (verified v3-v6): A row = lane&15, B col = lane&15,
// k = kt*32 + (lane>>4)*8 + j, C: col = lane&15, row = (lane>>4)*4 + reg.
__global__ __launch_bounds__(512) void k_scan(
    const float* __restrict__ thoughts, const int* __restrict__ isinit, const int* __restrict__ idx,
    const float* __restrict__ wihf, const float* __restrict__ whhf,
    const float* __restrict__ bihf, const float* __restrict__ bhhf,
    const float* __restrict__ wihb, const float* __restrict__ whhb,
    const float* __restrict__ bihb, const float* __restrict__ bhhb,
    float* __restrict__ newt)
{
  const int b0   = blockIdx.x * 2;
  const int tid  = threadIdx.x;
  const int w    = tid >> 6;          // wave 0..7
  const int lane = tid & 63;
  const int dir  = w >> 2;            // waves 0-3 fwd, 4-7 bwd
  const int wsub = w & 3;             // phase-A gate == phase-B l-slice
  const int lr   = lane & 15;
  const int hi   = lane >> 4;

  __shared__ __align__(16) _Float16 nt16[2][64 * 136]; // f16 state mirrors (2 x 17408 B)
  __shared__ __align__(16) _Float16 Zx16[2][2*8*64*4]; // input projections (2 x 8192 B)
  __shared__ __align__(16) _Float16 hb16[2][2][64];    // h states
  __shared__ int gall[2][512];
  __shared__ int flags[2][64];
  __shared__ int dirty[2][64];

  const float* wih = dir ? wihb : wihf;
  const float* whh = dir ? whhb : whhf;

  // phase-A B fragments: Wih[(wsub*64 + ni*16 + lr)][kt*32 + hi*8 + j]  (64 VGPR)
  h8 Bf[4][4];
  #pragma unroll
  for (int ni = 0; ni < 4; ni++){
    const float* wr = wih + (size_t)((wsub << 6) + (ni << 4) + lr) * 128 + (hi << 3);
    #pragma unroll
    for (int kt = 0; kt < 4; kt++) Bf[ni][kt] = load8f(wr + kt * 32);
    __builtin_amdgcn_sched_barrier(0);   // cap init liveness
  }
  // phase-B B fragments: Whh[(gg*64 + wsub*16 + lr)][kt*32 + hi*8 + j]  (32 VGPR)
  h8 Bh[4][2];
  #pragma unroll
  for (int gg = 0; gg < 4; gg++){
    const float* wr = whh + (size_t)((gg << 6) + (wsub << 4) + lr) * 64 + (hi << 3);
    #pragma unroll
    for (int kt = 0; kt < 2; kt++) Bh[gg][kt] = load8f(wr + kt * 32);
    __builtin_amdgcn_sched_barrier(0);
  }
  // bias for the Zx columns this lane writes (bih+bhh counted once, folded into Zx)
  float biasl[4];
  {
    const float* bih = dir ? bihb : bihf;
    const float* bhh = dir ? bhhb : bhhf;
    #pragma unroll
    for (int ni = 0; ni < 4; ni++){
      int n = (wsub << 6) + (ni << 4) + lr;
      biasl[ni] = bih[n] + bhh[n];
    }
  }

  #pragma unroll
  for (int q = 0; q < 2; q++){
    const float4* tf4 = (const float4*)(thoughts + (size_t)(b0 + q) * 8192);
    #pragma unroll
    for (int k2 = 0; k2 < 4; k2++){
      int id4 = tid + k2 * 512;                 // f4 index, 2048 per batch (32 f4 per row)
      float4 v = tf4[id4];
      *(h4*)&nt16[q][(id4 >> 5) * 136 + (id4 & 31) * 4] = pack_h4(v);
    }
  }
  { int p = tid;              gall[0][p] = idx[(size_t)b0 * 512 + p]; }
  { int p = tid + 512;        gall[1][p - 512] = idx[(size_t)b0 * 512 + p]; }
  if (tid < 128){ int q = tid >> 6, j = tid & 63;
    flags[q][j] = isinit[(b0 + q) * 64 + j]; dirty[q][j] = 0; }
  __syncthreads();

  #pragma unroll 1
  for (int i = 0; i < 64; i++){
    const int f0 = flags[0][i], f1 = flags[1][i];
    if (!(f0 | f1)) continue;           // block-uniform
    if (tid < 16){ int q = tid >> 3, j = tid & 7;
      if (q ? f1 : f0) dirty[q][gall[q][i * 8 + j]] = 1; }

    // ---- phase A (8 waves): Zx[q] = bias + X[q] @ Wih^T; A rows 0-7=batch0, 8-15=batch1 ----
    {
      const int qa = lr >> 3;
      const int grow = gall[qa][i * 8 + (lr & 7)];
      h8 Af[4];
      #pragma unroll
      for (int kt = 0; kt < 4; kt++)
        Af[kt] = *(const h8*)&nt16[qa][grow * 136 + kt * 32 + (hi << 3)];
      const int qo = hi >> 1, t0 = (hi & 1) << 2;      // C rows hi*4..+3 -> (qo, t0..t0+3)
      #pragma unroll
      for (int ni = 0; ni < 4; ni++){
        f4 acc = {0.0f, 0.0f, 0.0f, 0.0f};
        #pragma unroll
        for (int kt = 0; kt < 4; kt++)
          acc = __builtin_amdgcn_mfma_f32_16x16x32_f16(Af[kt], Bf[ni][kt], acc, 0, 0, 0);
        const int lp = (ni << 4) + lr;
        #pragma unroll
        for (int r = 0; r < 4; r++)
          Zx16[qo][(((dir << 3) + t0 + r) * 64 + lp) * 4 + wsub] = (_Float16)(acc[r] + biasl[ni]);
      }
    }
    __syncthreads();

    // ---- phase B: 8 steps, each wave (dir, l-slice) for BOTH batches (same Bh) ----
    float c0 = 0.0f, c1 = 0.0f;
    #pragma unroll
    for (int s = 0; s < 8; s++){
      const int tt = dir ? (7 - s) : s;
      #pragma unroll
      for (int q = 0; q < 2; q++){
        if (!(q ? f1 : f0)) continue;   // block-uniform
        uint2 zr = *(const uint2*)&Zx16[q][(((dir << 3) + tt) * 64 + (wsub << 4) + lr) * 4];
        h2 zlo = u32_h2(zr.x), zhi2 = u32_h2(zr.y);
        float z0 = (float)zlo.x, z1 = (float)zlo.y, z2 = (float)zhi2.x, z3 = (float)zhi2.y;
        if (s > 0){
          h8 a0 = *(const h8*)&hb16[q][dir][(hi << 3)];
          h8 a1 = *(const h8*)&hb16[q][dir][32 + (hi << 3)];
          f4 A;
          A = (f4){z0, 0.f, 0.f, 0.f};
          A = __builtin_amdgcn_mfma_f32_16x16x32_f16(a0, Bh[0][0], A, 0, 0, 0);
          A = __builtin_amdgcn_mfma_f32_16x16x32_f16(a1, Bh[0][1], A, 0, 0, 0);
          z0 = A[0];
          A = (f4){z1, 0.f, 0.f, 0.f};
          A = __builtin_amdgcn_mfma_f32_16x16x32_f16(a0, Bh[1][0], A, 0, 0, 0);
          A = __builtin_amdgcn_mfma_f32_16x16x32_f16(a1, Bh[1][1], A, 0, 0, 0);
          z1 = A[0];
          A = (f4){z2, 0.f, 0.f, 0.f};
          A = __builtin_amdgcn_mfma_f32_16x16x32_f16(a0, Bh[2][0], A, 0, 0, 0);
          A = __builtin_amdgcn_mfma_f32_16x16x32_f16(a1, Bh[2][1], A, 0, 0, 0);
          z2 = A[0];
          A = (f4){z3, 0.f, 0.f, 0.f};
          A = __builtin_amdgcn_mfma_f32_16x16x32_f16(a0, Bh[3][0], A, 0, 0, 0);
          A = __builtin_amdgcn_mfma_f32_16x16x32_f16(a1, Bh[3][1], A, 0, 0, 0);
          z3 = A[0];
        }
        float fi = fsig(z0);
        float ff = fsig(z1);
        float fg = ftanh(z2);
        float fo = fsig(z3);
        float cc = (q ? c1 : c0);
        cc = ff * cc + fi * fg;
        if (q) c1 = cc; else c0 = cc;
        float hn = fo * ftanh(cc);
        if (hi == 0){
          hb16[q][dir][(wsub << 4) + lr] = (_Float16)hn;
          nt16[q][gall[q][i * 8 + tt] * 136 + (dir << 6) + (wsub << 4) + lr] = (_Float16)hn;
        }
      }
      __syncthreads();
    }
  }

  __syncthreads();
  #pragma unroll
  for (int q = 0; q < 2; q++){
    const float4* tf4 = (const float4*)(thoughts + (size_t)(b0 + q) * 8192);
    float4* of4 = (float4*)(newt + (size_t)(b0 + q) * 8192);
    #pragma unroll
    for (int k2 = 0; k2 < 4; k2++){
      int id4 = tid + k2 * 512;
      int row = id4 >> 5, c4 = (id4 & 31) * 4;
      float4 v = tf4[id4];
      if (dirty[q][row]){
        h4 hv = *(const h4*)&nt16[q][row * 136 + c4];
        v.x = (float)hv.x; v.y = (float)hv.y; v.z = (float)hv.z; v.w = (float)hv.w;
      }
      of4[id4] = v;
    }
  }
}

// ---------------- actor_2 (MFMA f16): 32 rows per block, 256 threads ----------------
// x = relu(concat(thoughts,newt)) (32x256) @ a2w1^T (256->128) + b1 -> (32x128) @ a2w2^T
// (128->64) -> tanh. f16 inputs/weights, f32 accum; no discrete decisions downstream.
__global__ __launch_bounds__(256) void k_actor2(
    const float* __restrict__ thoughts, const float* __restrict__ newt,
    const _Float16* __restrict__ w1h, const float* __restrict__ b1,
    const _Float16* __restrict__ w2h, float* __restrict__ out)
{
  const int b0 = blockIdx.x * 32;
  const int tid = threadIdx.x;
  const int w = tid >> 6, lane = tid & 63, lr = lane & 15, hi = lane >> 4;
  const int mt = w & 1, nb = (w >> 1) << 6;

  __shared__ __align__(16) _Float16 Xc[32 * 264];   // relu(concat) f16, padded (16896 B)
  __shared__ __align__(16) _Float16 Ys[32 * 136];   // hidden f16, padded (8704 B)

  #pragma unroll
  for (int k2 = 0; k2 < 8; k2++){
    int id4 = tid + k2 * 256;              // f4 index over 32 rows x 64 f4
    int row = id4 >> 6, c4 = (id4 & 63) * 4;
    const float* src = (c4 < 128) ? (thoughts + (size_t)(b0 + row) * 128 + c4)
                                  : (newt + (size_t)(b0 + row) * 128 + (c4 - 128));
    float4 v = *(const float4*)src;
    *(h4*)&Xc[row * 264 + c4] = pack_h4_relu(v);
  }
  __syncthreads();

  // GEMM1: wave (mt, nb): rows mt*16.., cols nb..nb+63
  {
    h8 Af[8];
    #pragma unroll
    for (int kt = 0; kt < 8; kt++)
      Af[kt] = *(const h8*)&Xc[(mt * 16 + lr) * 264 + kt * 32 + (hi << 3)];
    #pragma unroll
    for (int ni = 0; ni < 4; ni++){
      const int n = nb + ni * 16 + lr;
      const _Float16* wr = w1h + (size_t)n * 256 + (hi << 3);
      f4 acc = {0.0f, 0.0f, 0.0f, 0.0f};
      #pragma unroll
      for (int kt = 0; kt < 8; kt++){
        h8 bfr = *(const h8*)(wr + kt * 32);
        acc = __builtin_amdgcn_mfma_f32_16x16x32_f16(Af[kt], bfr, acc, 0, 0, 0);
      }
      const float bb = b1[n];
      #pragma unroll
      for (int r = 0; r < 4; r++){
        int row = mt * 16 + (hi << 2) + r;
        Ys[row * 136 + n] = (_Float16)(acc[r] + bb);
      }
    }
  }
  __syncthreads();

  // GEMM2: wave (mt, ni0): rows mt*16.., cols (ni0..ni0+1)*16
  {
    const int ni0 = (w >> 1) << 1;
    h8 Ag[4];
    #pragma unroll
    for (int kt = 0; kt < 4; kt++)
      Ag[kt] = *(const h8*)&Ys[(mt * 16 + lr) * 136 + kt * 32 + (hi << 3)];
    #pragma unroll
    for (int nj = 0; nj < 2; nj++){
      const int n = (ni0 + nj) * 16 + lr;
      const _Float16* wr = w2h + (size_t)n * 128 + (hi << 3);
      f4 acc = {0.0f, 0.0f, 0.0f, 0.0f};
      #pragma unroll
      for (int kt = 0; kt < 4; kt++){
        h8 bfr = *(const h8*)(wr + kt * 32);
        acc = __builtin_amdgcn_mfma_f32_16x16x32_f16(Ag[kt], bfr, acc, 0, 0, 0);
      }
      #pragma unroll
      for (int r = 0; r < 4; r++){
        int row = mt * 16 + (hi << 2) + r;
        out[(size_t)(b0 + row) * 64 + n] = ftanh(acc[r]);
      }
    }
  }
}

extern "C" void kernel_launch(void* const* d_in, const int* in_sizes, int n_in,
                              void* d_out, int out_size, void* d_ws, size_t ws_size,
                              hipStream_t stream)
{
  const float* obs  = (const float*)d_in[0];
  const float* w1   = (const float*)d_in[1];
  const float* b1   = (const float*)d_in[2];
  const float* lng  = (const float*)d_in[3];
  const float* lnb  = (const float*)d_in[4];
  const float* w2   = (const float*)d_in[5];
  const float* b2   = (const float*)d_in[6];
  const float* aw1  = (const float*)d_in[7];
  const float* ab1  = (const float*)d_in[8];
  const float* aw2  = (const float*)d_in[9];
  const float* ab2  = (const float*)d_in[10];
  const float* aw3  = (const float*)d_in[11];
  const float* ab3  = (const float*)d_in[12];
  const float* wihf = (const float*)d_in[13];
  const float* whhf = (const float*)d_in[14];
  const float* bihf = (const float*)d_in[15];
  const float* bhhf = (const float*)d_in[16];
  const float* wihb = (const float*)d_in[17];
  const float* whhb = (const float*)d_in[18];
  const float* bihb = (const float*)d_in[19];
  const float* bhhb = (const float*)d_in[20];
  const float* a2w1 = (const float*)d_in[21];
  const float* a2b1 = (const float*)d_in[22];
  const float* a2w2 = (const float*)d_in[23];

  float* thoughts = (float*)d_ws;                       // 33.5 MB
  float* newt     = thoughts + (size_t)ROWS * 128;      // 33.5 MB
  int*   isinit   = (int*)(newt + (size_t)ROWS * 128);  // 256 KB
  int*   idxb     = isinit + ROWS;                      // 2 MB
  _Float16* w1h   = (_Float16*)(idxb + (size_t)ROWS * 8);  // 64 KB
  _Float16* w2h   = w1h + 32768;                           // 16 KB

  hipLaunchKernelGGL(k_cvt, dim3(128), dim3(256), 0, stream, a2w1, a2w2, w1h, w2h);
  hipLaunchKernelGGL(k_actor1, dim3(ROWS / 8), dim3(128), 0, stream,
                     obs, w1, b1, lng, lnb, w2, b2, aw1, ab1, aw2, ab2, aw3, ab3,
                     thoughts, isinit);
  hipLaunchKernelGGL(k_groups, dim3(NB), dim3(256), 0, stream, thoughts, idxb);
  hipLaunchKernelGGL(k_scan, dim3(NB / 2), dim3(512), 0, stream,
                     thoughts, isinit, idxb,
                     wihf, whhf, bihf, bhhf, wihb, whhb, bihb, bhhb, newt);
  hipLaunchKernelGGL(k_actor2, dim3(ROWS / 32), dim3(256), 0, stream,
                     thoughts, newt, w1h, a2b1, w2h, (float*)d_out);
}